// Round 16
// baseline (125.357 us; speedup 1.0000x reference)
//
#include <hip/hip_runtime.h>
#include <hip/hip_bf16.h>
#include <math.h>

// Problem constants
#define DM 1024    // d_model
#define DS 16      // d_state
#define BB 4       // batch
#define LL 2048    // seq len
#define LC 32      // scan chunk length
#define NC (LL/LC) // 64 chunks
#define MT 8192    // B*L tokens
#define NT64 16    // GEMM k-steps (DM/64)

typedef __attribute__((ext_vector_type(8))) short short8;
typedef __attribute__((ext_vector_type(4))) short short4v;
typedef __attribute__((ext_vector_type(4))) float floatx4;

__device__ __forceinline__ float softplus_fast(float v) {
  return fmaxf(v, 0.f) + __logf(1.f + __expf(-fabsf(v)));
}
__device__ __forceinline__ float bf2f(short s) {
  union { short s2[2]; float f; } u; u.s2[0] = 0; u.s2[1] = s; return u.f;
}

// ---- Kernel 1: convert. Blocks 0..2047: X -> Xb (linear) AND XbT (transposed,
// via LDS 64x64 tile, pitch 65). Blocks 2048..2575: [W_dt|W_B|W_C] -> Wx. ----
__global__ __launch_bounds__(256) void convert_kernel(
    const float* __restrict__ X, const float* __restrict__ W_dt,
    const float* __restrict__ WB, const float* __restrict__ WC,
    __hip_bfloat16* __restrict__ Xb, __hip_bfloat16* __restrict__ XbT,
    __hip_bfloat16* __restrict__ Wx)
{
  const int tid = threadIdx.x;
  if (blockIdx.x < 2048) {
    __shared__ __hip_bfloat16 tile[64 * 65];   // pitch 65
    const int tb = blockIdx.x;
    const int t0 = (tb & 127) * 64;    // token tile
    const int d0 = (tb >> 7) * 64;     // channel tile
    const int tr  = tid >> 4;          // 0..15
    const int tc4 = (tid & 15) * 4;    // 0..60
#pragma unroll
    for (int p = 0; p < 4; ++p) {
      const int row = p * 16 + tr;
      const float4 v = *(const float4*)&X[(size_t)(t0 + row) * DM + d0 + tc4];
      union { short4v v4; __hip_bfloat16 h[4]; } pk;
      pk.h[0] = __float2bfloat16(v.x); pk.h[1] = __float2bfloat16(v.y);
      pk.h[2] = __float2bfloat16(v.z); pk.h[3] = __float2bfloat16(v.w);
      tile[row * 65 + tc4 + 0] = pk.h[0];
      tile[row * 65 + tc4 + 1] = pk.h[1];
      tile[row * 65 + tc4 + 2] = pk.h[2];
      tile[row * 65 + tc4 + 3] = pk.h[3];
      *(short4v*)&Xb[(size_t)(t0 + row) * DM + d0 + tc4] = pk.v4;
    }
    __syncthreads();
#pragma unroll
    for (int p = 0; p < 4; ++p) {
      const int drow = p * 16 + tr;
      union { short4v v4; __hip_bfloat16 h[4]; } pk;
#pragma unroll
      for (int q = 0; q < 4; ++q)
        pk.h[q] = tile[(tc4 + q) * 65 + drow];
      *(short4v*)&XbT[(size_t)(d0 + drow) * MT + t0 + tc4] = pk.v4;
    }
    return;
  }
  // W part: unit = 8 elems. W_dt | WB | WC (rows 0..1055).
  const size_t u0 = (size_t)(blockIdx.x - 2048) * 256 + tid;  // < 135168
  const size_t NW = (size_t)DM * DM / 8;   // 131072
  const size_t NB = (size_t)DS * DM / 8;   //   2048
  const float* src;
  __hip_bfloat16* dst;
  size_t u;
  if (u0 < NW)               { src = W_dt; dst = Wx;                       u = u0; }
  else if (u0 < NW + NB)     { src = WB;   dst = Wx + (size_t)1024 * DM;   u = u0 - NW; }
  else if (u0 < NW + 2 * NB) { src = WC;   dst = Wx + (size_t)1040 * DM;   u = u0 - NW - NB; }
  else return;
  const float4 a = *(const float4*)&src[u * 8];
  const float4 b = *(const float4*)&src[u * 8 + 4];
  union { short8 v; __hip_bfloat16 h[8]; } o;
  o.h[0] = __float2bfloat16(a.x); o.h[1] = __float2bfloat16(a.y);
  o.h[2] = __float2bfloat16(a.z); o.h[3] = __float2bfloat16(a.w);
  o.h[4] = __float2bfloat16(b.x); o.h[5] = __float2bfloat16(b.y);
  o.h[6] = __float2bfloat16(b.z); o.h[7] = __float2bfloat16(b.w);
  *(short8*)&dst[u * 8] = o.v;
}

// ---- Kernel 2: DTt = softplus(Xb @ W_dt^T + b), Bp/Cp via SPLIT-K. ----
// Grid EXACTLY 512 = 16 ct x 32 rg (2 blocks/CU, zero dispatch tail; the old
// 544-grid spent ~half its time in a 32-block tail -- occupancy 26% matched).
// Block ct also computes the B/C partial for K-slice [64ct,64ct+64): BC weight
// frags preloaded global->reg (8 VGPR, drain at first vmcnt(5)); 8 extra MFMAs
// at phase t==ct; f32 atomicAdd epilogue to memset-zeroed BP/CP.
__global__ __launch_bounds__(512, 4) void gemm_dt_mfma(
    const __hip_bfloat16* __restrict__ Xb, const __hip_bfloat16* __restrict__ Wx,
    const float* __restrict__ bias, __hip_bfloat16* __restrict__ DTt,
    float* __restrict__ BP, float* __restrict__ CP)
{
  __shared__ short As[2][256 * 64];   // 32KB per buf
  __shared__ short Bs[2][64 * 64];    //  8KB per buf
  const int tid  = threadIdx.x;       // 0..511
  const int lane = tid & 63;
  const int wid  = tid >> 6;          // 0..7
  const int wm   = wid >> 1, wn = wid & 1;   // 4M x 2N waves

  // XCD swizzle: 512 = 8 XCDs x 64 (bijective).
  const int bid  = blockIdx.x;
  const int tile = (bid & 7) * 64 + (bid >> 3);
  const int row0 = (tile >> 4) * 256;   // 32 row groups
  const int ct   = tile & 15;           // 16 col tiles
  const int col0 = ct * 64;

  const floatx4 zero = {0.f, 0.f, 0.f, 0.f};
  floatx4 acc[4][2];
#pragma unroll
  for (int i = 0; i < 4; ++i)
#pragma unroll
    for (int j = 0; j < 2; ++j) acc[i][j] = zero;
  floatx4 acc_bc[4];
#pragma unroll
  for (int i = 0; i < 4; ++i) acc_bc[i] = zero;

  auto STAGE = [&](int buf, int t) {
    const int k0 = t * 64;
#pragma unroll
    for (int q = 0; q < 4; ++q) {
      const int fe = q * 512 + tid;
      const int r  = fe >> 3;
      const int kk = (fe & 7) ^ (r & 7);
      __builtin_amdgcn_global_load_lds(
          (const __attribute__((address_space(1))) void*)&Xb[(size_t)(row0 + r) * DM + k0 + kk * 8],
          (__attribute__((address_space(3))) void*)&As[buf][fe * 8], 16, 0, 0);
    }
    {
      const int fe = tid;
      const int r  = fe >> 3;
      const int kk = (fe & 7) ^ (r & 7);
      __builtin_amdgcn_global_load_lds(
          (const __attribute__((address_space(1))) void*)&Wx[(size_t)(col0 + r) * DM + k0 + kk * 8],
          (__attribute__((address_space(3))) void*)&Bs[buf][fe * 8], 16, 0, 0);
    }
  };

  const int fr = lane & 15;
  const int ks = lane >> 4;

  // BC weight fragments for this block's K-slice: Wx rows 1024+wn*16+fr
  // (wn=0 -> W_B, wn=1 -> W_C), k = ct*64 + s*32 + ks*8.
  const size_t bcrow = (size_t)(1024 + wn * 16 + fr) * DM + ct * 64 + ks * 8;
  short8 bc0, bc1;

  STAGE(0, 0);
  bc0 = *(const short8*)&Wx[bcrow];
  bc1 = *(const short8*)&Wx[bcrow + 32];

  int cur = 0;
  for (int t = 0; t < NT64; ++t) {
    if (t + 1 < NT64) {
      STAGE(cur ^ 1, t + 1);
      asm volatile("s_waitcnt vmcnt(5)" ::: "memory");   // drains prologue (7) + t's 5
    } else {
      asm volatile("s_waitcnt vmcnt(0)" ::: "memory");
    }
    __builtin_amdgcn_s_barrier();
    __builtin_amdgcn_sched_barrier(0);

    short8 af[4][2], bfr[2][2];
#pragma unroll
    for (int i = 0; i < 4; ++i) {
      const int ar = wm * 64 + i * 16 + fr;
#pragma unroll
      for (int s = 0; s < 2; ++s) {
        const int ch = (ks + 4 * s) ^ (ar & 7);
        af[i][s] = *(const short8*)&As[cur][ar * 64 + ch * 8];
      }
    }
#pragma unroll
    for (int j = 0; j < 2; ++j) {
      const int br = wn * 32 + j * 16 + fr;
#pragma unroll
      for (int s = 0; s < 2; ++s) {
        const int ch = (ks + 4 * s) ^ (br & 7);
        bfr[j][s] = *(const short8*)&Bs[cur][br * 64 + ch * 8];
      }
    }
    __builtin_amdgcn_s_setprio(1);
#pragma unroll
    for (int s = 0; s < 2; ++s)
#pragma unroll
      for (int i = 0; i < 4; ++i)
#pragma unroll
        for (int j = 0; j < 2; ++j)
          acc[i][j] = __builtin_amdgcn_mfma_f32_16x16x32_bf16(af[i][s], bfr[j][s], acc[i][j], 0, 0, 0);
    __builtin_amdgcn_s_setprio(0);
    if (t == ct) {   // block-uniform: split-K B/C contribution for this K-slice
#pragma unroll
      for (int i = 0; i < 4; ++i) {
        acc_bc[i] = __builtin_amdgcn_mfma_f32_16x16x32_bf16(af[i][0], bc0, acc_bc[i], 0, 0, 0);
        acc_bc[i] = __builtin_amdgcn_mfma_f32_16x16x32_bf16(af[i][1], bc1, acc_bc[i], 0, 0, 0);
      }
    }
    __builtin_amdgcn_sched_barrier(0);

    if (t + 1 < NT64) {
      __builtin_amdgcn_s_barrier();
      cur ^= 1;
    }
  }

  // epilogue. C/D layout: col=lane&15, row=(lane>>4)*4+r
  const int cl = lane & 15;
  const int rg = lane >> 4;
  // dt path: bias + softplus -> bf16, TRANSPOSED store DTt[col][rowbase..+3]
#pragma unroll
  for (int i = 0; i < 4; ++i) {
    const size_t rowbase = (size_t)(row0 + wm * 64 + i * 16 + rg * 4);
#pragma unroll
    for (int j = 0; j < 2; ++j) {
      const int col = col0 + wn * 32 + j * 16 + cl;
      union { short4v v4; __hip_bfloat16 h[4]; } pk;
#pragma unroll
      for (int r = 0; r < 4; ++r)
        pk.h[r] = __float2bfloat16(softplus_fast(acc[i][j][r] + bias[col]));
      *(short4v*)&DTt[(size_t)col * MT + rowbase] = pk.v4;
    }
  }
  // B/C split-K partial: atomicAdd into BP (wn=0) / CP (wn=1)
  float* dstBC = (wn == 0) ? BP : CP;
#pragma unroll
  for (int i = 0; i < 4; ++i) {
#pragma unroll
    for (int r = 0; r < 4; ++r) {
      const size_t row = (size_t)(row0 + wm * 64 + i * 16 + rg * 4 + r);
      atomicAdd(&dstBC[row * DS + cl], acc_bc[i][r]);
    }
  }
}

// ---- Kernel 3: per-chunk local scan (pass A), n-SPLIT, TRANSPOSED dt/x loads ----
__global__ __launch_bounds__(256) void scan_partial_kernel(
    const __hip_bfloat16* __restrict__ DTt, const __hip_bfloat16* __restrict__ XbT,
    const float* __restrict__ Bp, const float* __restrict__ A_log,
    float* __restrict__ SD, __hip_bfloat16* __restrict__ HP)
{
  __shared__ float sB[LC * DS];   // 2KB
  const int tid = threadIdx.x;
  const int d  = blockIdx.x * 128 + (tid >> 1);
  const int nh = tid & 1;
  const int c = blockIdx.y;
  const int b = blockIdx.z;
  const int l0 = c * LC;

  if (tid < LC * DS / 4)
    ((float4*)sB)[tid] = ((const float4*)&Bp[((size_t)b * LL + l0) * DS])[tid];

  float A[8], h[8];
  float sdt = 0.f;
  const float4* arow = (const float4*)&A_log[(size_t)d * DS + nh * 8];
  {
    const float4 a0 = arow[0], a1 = arow[1];
    A[0]=-__expf(a0.x); A[1]=-__expf(a0.y); A[2]=-__expf(a0.z); A[3]=-__expf(a0.w);
    A[4]=-__expf(a1.x); A[5]=-__expf(a1.y); A[6]=-__expf(a1.z); A[7]=-__expf(a1.w);
  }
#pragma unroll
  for (int n = 0; n < 8; ++n) h[n] = 0.f;

  const __hip_bfloat16* dT = &DTt[(size_t)d * MT + (size_t)b * LL + l0];
  const __hip_bfloat16* xT = &XbT[(size_t)d * MT + (size_t)b * LL + l0];
  short8 d8 = *(const short8*)dT;
  short8 x8 = *(const short8*)xT;
  __syncthreads();

  for (int l = 0; l < LC; l += 8) {
    short8 d8n, x8n;
    if (l + 8 < LC) {
      d8n = *(const short8*)(dT + l + 8);
      x8n = *(const short8*)(xT + l + 8);
    }
#pragma unroll
    for (int u = 0; u < 8; ++u) {
      const float dtv = bf2f(d8[u]), xv = bf2f(x8[u]);
      const float dx = dtv * xv;
      sdt += dtv;
      const float4 b0 = ((const float4*)sB)[(l+u)*4 + nh*2 + 0];
      const float4 b1 = ((const float4*)sB)[(l+u)*4 + nh*2 + 1];
      const float bb[8] = {b0.x,b0.y,b0.z,b0.w, b1.x,b1.y,b1.z,b1.w};
#pragma unroll
      for (int n = 0; n < 8; ++n) {
        const float dA = __expf(dtv * A[n]);
        h[n] = fmaf(dA, h[n], dx * bb[n]);
      }
    }
    d8 = d8n; x8 = x8n;
  }
  if (nh == 0) SD[((size_t)b * NC + c) * DM + d] = sdt;
  const size_t o = (((size_t)b * NC + c) * DM + d) * DS + nh * 8;
  union { short8 v; __hip_bfloat16 h[8]; } pk;
#pragma unroll
  for (int n = 0; n < 8; ++n) pk.h[n] = __float2bfloat16(h[n]);
  *(short8*)&HP[o] = pk.v;
}

// ---- Kernel 4: combine chunk prefixes (sequential over NC=64), HP bf16 in-place ----
__global__ __launch_bounds__(256) void combine_kernel(
    const float* __restrict__ SD, const float* __restrict__ A_log,
    __hip_bfloat16* HP)
{
  const int idx = blockIdx.x * 256 + threadIdx.x;  // over B*DM*DS = 65536
  const int b  = idx >> 14;
  const int dn = idx & 16383;        // = d*DS + n
  const int d  = dn >> 4;
  const float A = -__expf(A_log[dn]);
  float h = 0.f;
#pragma unroll 4
  for (int c = 0; c < NC; ++c) {
    const size_t o = (((size_t)b * NC + c) << 14) + dn;
    const float p  = __expf(SD[((size_t)b * NC + c) * DM + d] * A);
    const float hp = __bfloat162float(HP[o]);
    HP[o] = __float2bfloat16(h);     // Hin for chunk c (entry state)
    h = fmaf(p, h, hp);
  }
}

// ---- Kernel 5: final scan + output (pass B), n-SPLIT, transposed loads ----
__global__ __launch_bounds__(256) void scan_final_kernel(
    const __hip_bfloat16* __restrict__ DTt, const __hip_bfloat16* __restrict__ XbT,
    const float* __restrict__ Bp, const float* __restrict__ Cp,
    const float* __restrict__ A_log, const float* __restrict__ Dvec,
    const __hip_bfloat16* __restrict__ Hin, float* __restrict__ Y)
{
  __shared__ float sB[LC * DS], sC[LC * DS];   // 2KB + 2KB
  const int tid = threadIdx.x;
  const int d  = blockIdx.x * 128 + (tid >> 1);
  const int nh = tid & 1;
  const int c = blockIdx.y;
  const int b = blockIdx.z;
  const int l0 = c * LC;

  if (tid < 128)  ((float4*)sB)[tid] = ((const float4*)&Bp[((size_t)b * LL + l0) * DS])[tid];
  else            ((float4*)sC)[tid - 128] = ((const float4*)&Cp[((size_t)b * LL + l0) * DS])[tid - 128];

  float A[8], h[8];
  const float4* arow = (const float4*)&A_log[(size_t)d * DS + nh * 8];
  {
    const float4 a0 = arow[0], a1 = arow[1];
    A[0]=-__expf(a0.x); A[1]=-__expf(a0.y); A[2]=-__expf(a0.z); A[3]=-__expf(a0.w);
    A[4]=-__expf(a1.x); A[5]=-__expf(a1.y); A[6]=-__expf(a1.z); A[7]=-__expf(a1.w);
  }
  const size_t o = (((size_t)b * NC + c) * DM + d) * DS + nh * 8;
  {
    const short8 hv = *(const short8*)&Hin[o];
#pragma unroll
    for (int n = 0; n < 8; ++n) h[n] = bf2f(hv[n]);
  }
  const float Dd = Dvec[d];
  const size_t tok0 = (size_t)b * LL + l0;
  const __hip_bfloat16* dT = &DTt[(size_t)d * MT + tok0];
  const __hip_bfloat16* xT = &XbT[(size_t)d * MT + tok0];
  short8 d8 = *(const short8*)dT;
  short8 x8 = *(const short8*)xT;
  __syncthreads();

  for (int l = 0; l < LC; l += 8) {
    short8 d8n, x8n;
    if (l + 8 < LC) {
      d8n = *(const short8*)(dT + l + 8);
      x8n = *(const short8*)(xT + l + 8);
    }
#pragma unroll
    for (int u = 0; u < 8; ++u) {
      const float dtv = bf2f(d8[u]), xv = bf2f(x8[u]);
      const float dx = dtv * xv;
      const float4 b0 = ((const float4*)sB)[(l+u)*4 + nh*2 + 0];
      const float4 b1 = ((const float4*)sB)[(l+u)*4 + nh*2 + 1];
      const float bb[8] = {b0.x,b0.y,b0.z,b0.w, b1.x,b1.y,b1.z,b1.w};
      const float4 c0 = ((const float4*)sC)[(l+u)*4 + nh*2 + 0];
      const float4 c1 = ((const float4*)sC)[(l+u)*4 + nh*2 + 1];
      const float cc[8] = {c0.x,c0.y,c0.z,c0.w, c1.x,c1.y,c1.z,c1.w};
      float y = 0.f;
#pragma unroll
      for (int n = 0; n < 8; ++n) {
        const float dA = __expf(dtv * A[n]);
        h[n] = fmaf(dA, h[n], dx * bb[n]);
        y = fmaf(h[n], cc[n], y);
      }
      y += __shfl_xor(y, 1, 64);           // combine the two state halves
      if (nh == 0) Y[(tok0 + l + u) * DM + d] = fmaf(Dd, xv, y);
    }
    d8 = d8n; x8 = x8n;
  }
}

// ---- launch ----
// Workspace (float slots):
//   DTt : MT*DM bf16 (transposed [d][token]) = 4194304
//   BP  : MT*DS f32                          =  131072
//   CP  : MT*DS f32                          =  131072   (contiguous after BP)
//   Xb  : MT*DM bf16 (linear, GEMM)          = 4194304
//   XbT : MT*DM bf16 (transposed, scans)     = 4194304
//   Wx  : 1056*DM bf16 (alloc 1088)          =  557056
//   SD  : BB*NC*DM f32                       =  262144
//   HP  : BB*NC*DM*DS bf16                   = 2097152
// total = 15,761,408 floats = 63,045,632 bytes.
extern "C" void kernel_launch(void* const* d_in, const int* in_sizes, int n_in,
                              void* d_out, int out_size, void* d_ws, size_t ws_size,
                              hipStream_t stream)
{
  const float* x     = (const float*)d_in[0];
  const float* W_dt  = (const float*)d_in[1];
  const float* b_dt  = (const float*)d_in[2];
  const float* W_B   = (const float*)d_in[3];
  const float* W_C   = (const float*)d_in[4];
  const float* A_log = (const float*)d_in[5];
  const float* Dv    = (const float*)d_in[6];
  float* Y  = (float*)d_out;
  float* ws = (float*)d_ws;

  __hip_bfloat16* DTt = (__hip_bfloat16*)ws;
  float* BP = ws + (size_t)MT * DM / 2;
  float* CP = BP + (size_t)MT * DS;
  __hip_bfloat16* Xb  = (__hip_bfloat16*)(CP + (size_t)MT * DS);
  __hip_bfloat16* XbT = Xb + (size_t)MT * DM;
  __hip_bfloat16* Wx  = XbT + (size_t)MT * DM;
  float* SD = (float*)(Wx + (size_t)1088 * DM);
  __hip_bfloat16* HP = (__hip_bfloat16*)(SD + (size_t)BB * NC * DM);

  hipMemsetAsync(BP, 0, (size_t)2 * MT * DS * sizeof(float), stream);  // BP+CP
  convert_kernel<<<2576, 256, 0, stream>>>(x, W_dt, W_B, W_C, Xb, XbT, Wx);
  gemm_dt_mfma<<<512, 512, 0, stream>>>(Xb, Wx, b_dt, DTt, BP, CP);
  scan_partial_kernel<<<dim3(DM * 2 / 256, NC, BB), 256, 0, stream>>>(DTt, XbT, BP, A_log, SD, HP);
  combine_kernel<<<(BB * DM * DS) / 256, 256, 0, stream>>>(SD, A_log, HP);
  scan_final_kernel<<<dim3(DM * 2 / 256, NC, BB), 256, 0, stream>>>(DTt, XbT, BP, CP, A_log, Dv, HP, Y);
}